// Round 9
// baseline (76.905 us; speedup 1.0000x reference)
//
#include <hip/hip_runtime.h>
#include <stdint.h>

// ---------------------------------------------------------------------------
// FastHelgasonLayer: weights are IFFTs of 16-sparse spectra => exactly rank-32.
//   W_fc = U_fc(2048x32)V_fc(32x8192), W_proj = U_pr(8192x32)V_pr(32x2048)
// Round 9: NO factor arrays, NO k_build. Every kernel synthesizes its MFMA
// operand fragments in-register from the 16 coeffs (exact integer phases).
// 3 kernels: k_t1 (x@U_fc), k_mid (gelu middle, reg-only), k_out (T2@V_pr).
// ---------------------------------------------------------------------------

typedef short bfrag8 __attribute__((ext_vector_type(8)));   // 8 bf16
typedef short bfrag4 __attribute__((ext_vector_type(4)));   // 4 bf16
typedef float f32x4  __attribute__((ext_vector_type(4)));

#define LMASK 8388607u      // 2^23 - 1
#define TWO_PI_OVER_L 7.4901405658478575e-7f

__device__ __forceinline__ unsigned short f2bf(float f) {
    unsigned u = __float_as_uint(f);
    u = (u + 0x7FFFu + ((u >> 16) & 1u)) >> 16;   // RTN-even
    return (unsigned short)u;
}
__device__ __forceinline__ float bf2f(unsigned short h) {
    unsigned u = ((unsigned)h) << 16;
    return __builtin_bit_cast(float, u);
}
__device__ __forceinline__ unsigned pk2bf(float a, float b) {
    unsigned ua = __float_as_uint(a) + 0x8000u;
    unsigned ub = __float_as_uint(b) + 0x8000u;
    return __builtin_amdgcn_perm(ub, ua, 0x07060302u);
}
__device__ __forceinline__ float gelu_fast(float x) {
    float xx = x * x;
    float p  = fmaf(xx, 0.044715f, 1.0f);
    float t  = (x * p) * -2.3022083f;             // -2*sqrt(2/pi)*log2(e)
    float e  = __builtin_amdgcn_exp2f(t);
    return x * __builtin_amdgcn_rcpf(1.0f + e);
}
__device__ __forceinline__ void sc_ph(unsigned ph, float& sn, float& cs) {
    __sincosf((float)ph * TWO_PI_OVER_L, &sn, &cs);
}

#if defined(__has_builtin)
#if __has_builtin(__builtin_amdgcn_mfma_f32_16x16x16bf16_1k)
#define HAVE_MFMA16_1K 1
#endif
#endif
__device__ __forceinline__ void mfma16(f32x4& acc, bfrag4 a, bfrag4 b) {
#ifdef HAVE_MFMA16_1K
    acc = __builtin_amdgcn_mfma_f32_16x16x16bf16_1k(a, b, acc, 0, 0, 0);
#else
    asm("v_mfma_f32_16x16x16_bf16 %0, %1, %2, %0" : "+v"(acc) : "v"(a), "v"(b));
#endif
}

// dedup (last-write-wins): coeff kk survives only if no later j has same index
__device__ __forceinline__ bool keep_coef(const int* __restrict__ idx, int kk) {
    int v = idx[kk];
    bool keep = true;
    for (int j = kk + 1; j < 16; ++j) keep = keep && (idx[j] != v);
    return keep;
}

// ------------------ kernel 1: T1 = x @ U_fc  (512 blocks) -------------------
// B-operand rows (U_fc^T) synthesized in-register: row r=2k+p over i (d_model):
//   val = p ? a*sin+b*cos : a*cos-b*sin,  phase = ((idx[k]<<12)*i) mod 2^23
__global__ __launch_bounds__(512, 4) void k_t1(
    const float* __restrict__ x,                 // [8192 tok][2048]
    const float* __restrict__ fcr, const float* __restrict__ fci,
    const int* __restrict__ fidx,  const float* __restrict__ fcs,
    unsigned short* __restrict__ t1)             // [512 g][16 tok][32 r] bf16
{
    __shared__ float red[8 * 512];
    const int tid  = threadIdx.x;
    const int w    = tid >> 6;
    const int lane = tid & 63;
    const int lr   = lane & 15;
    const int hi   = lane >> 4;
    const size_t tok0 = (size_t)blockIdx.x * 16;

    const float sc = fcs[0] * (1.0f / 8388608.0f);
    const int p   = lr & 1;
    const int kk0 = lr >> 1, kk1 = 8 + (lr >> 1);
    unsigned s0, s1; float a0, b0, a1, b1;
    {
        bool k0 = keep_coef(fidx, kk0), k1 = keep_coef(fidx, kk1);
        s0 = (((unsigned)fidx[kk0]) << 12) & LMASK;
        s1 = (((unsigned)fidx[kk1]) << 12) & LMASK;
        a0 = k0 ? fcr[kk0] * sc : 0.f;  b0 = k0 ? fci[kk0] * sc : 0.f;
        a1 = k1 ? fcr[kk1] * sc : 0.f;  b1 = k1 ? fci[kk1] * sc : 0.f;
    }

    f32x4 acc[2];
    { f32x4 z = {0.f,0.f,0.f,0.f}; acc[0] = z; acc[1] = z; }
    #pragma unroll 2
    for (int s = 0; s < 8; ++s) {
        int k = w * 256 + s * 32 + hi * 8;
        const float* xp = x + (tok0 + lr) * 2048 + k;
        float4 v0 = *(const float4*)xp;
        float4 v1 = *(const float4*)(xp + 4);
        uint4 aw = make_uint4(pk2bf(v0.x, v0.y), pk2bf(v0.z, v0.w),
                              pk2bf(v1.x, v1.y), pk2bf(v1.z, v1.w));
        bfrag8 af = __builtin_bit_cast(bfrag8, aw);
        float e0[8], e1[8];
        #pragma unroll
        for (int t = 0; t < 8; ++t) {
            float sn, cs;
            sc_ph((s0 * (unsigned)(k + t)) & LMASK, sn, cs);
            e0[t] = p ? fmaf(a0, sn, b0 * cs) : fmaf(a0, cs, -b0 * sn);
            sc_ph((s1 * (unsigned)(k + t)) & LMASK, sn, cs);
            e1[t] = p ? fmaf(a1, sn, b1 * cs) : fmaf(a1, cs, -b1 * sn);
        }
        uint4 bw0 = make_uint4(pk2bf(e0[0], e0[1]), pk2bf(e0[2], e0[3]),
                               pk2bf(e0[4], e0[5]), pk2bf(e0[6], e0[7]));
        uint4 bw1 = make_uint4(pk2bf(e1[0], e1[1]), pk2bf(e1[2], e1[3]),
                               pk2bf(e1[4], e1[5]), pk2bf(e1[6], e1[7]));
        bfrag8 bf0 = __builtin_bit_cast(bfrag8, bw0);
        bfrag8 bf1 = __builtin_bit_cast(bfrag8, bw1);
        acc[0] = __builtin_amdgcn_mfma_f32_16x16x32_bf16(af, bf0, acc[0], 0, 0, 0);
        acc[1] = __builtin_amdgcn_mfma_f32_16x16x32_bf16(af, bf1, acc[1], 0, 0, 0);
    }
    #pragma unroll
    for (int nj = 0; nj < 2; ++nj)      // C: row=tok(4hi+r), col=r(nj*16+lr)
        #pragma unroll
        for (int r = 0; r < 4; ++r)
            red[w * 512 + (hi * 4 + r) * 32 + nj * 16 + lr] = acc[nj][r];
    __syncthreads();
    float s = 0.f;
    #pragma unroll
    for (int w2 = 0; w2 < 8; ++w2) s += red[w2 * 512 + tid];
    t1[(size_t)blockIdx.x * 512 + tid] = f2bf(s);
}

// -------- kernel 2: middle loop (16 fc x 32 gtiles), factors in-register ----
__global__ __launch_bounds__(512, 4) void k_mid(
    const unsigned short* __restrict__ t1,       // [512 g][512]
    const int* __restrict__ fidx,
    const int* __restrict__ pidx,
    const float* __restrict__ prr, const float* __restrict__ pri,
    const float* __restrict__ prs,
    const float* __restrict__ fcb,               // [8192]
    unsigned short* __restrict__ t2p)            // [16 fc][512 g][512] bf16
{
    __shared__ float red[2 * 8 * 512];           // 32 KB
    const int tid  = threadIdx.x;
    const int w    = tid >> 6;
    const int lane = tid & 63;
    const int lr   = lane & 15;
    const int hi   = lane >> 4;
    const int fc   = blockIdx.x;            // f-chunk 0..15 (512 f each)
    const int g0   = blockIdx.y * 16;       // token-group base (16 groups)
    const int fb_w = fc * 512 + w * 64;     // wave's 64-f base

    // ---- synthesize V_fc^T A-fragments (unit exponentials) -----------------
    bfrag8 va0[2], va1[2];
    f32x4  cb0[2], cb1[2];
    unsigned skv[4];
    #pragma unroll
    for (int c = 0; c < 4; ++c) skv[c] = ((unsigned)fidx[hi * 4 + c]) & LMASK;
    #pragma unroll
    for (int sl = 0; sl < 2; ++sl) {
        #pragma unroll
        for (int rv = 0; rv < 2; ++rv) {         // rv=0: rows lr, rv=1: rows 16+lr
            int j = fb_w + sl * 32 + rv * 16 + lr;
            unsigned m = ((unsigned)j) >> 1;
            int pj = j & 1;
            float v[8];
            #pragma unroll
            for (int c = 0; c < 4; ++c) {
                float sn, cs;
                sc_ph((skv[c] * m) & LMASK, sn, cs);
                v[2 * c]     = pj ? sn : cs;
                v[2 * c + 1] = pj ? cs : -sn;
            }
            uint4 pw = make_uint4(pk2bf(v[0], v[1]), pk2bf(v[2], v[3]),
                                  pk2bf(v[4], v[5]), pk2bf(v[6], v[7]));
            if (rv == 0) va0[sl] = __builtin_bit_cast(bfrag8, pw);
            else         va1[sl] = __builtin_bit_cast(bfrag8, pw);
        }
        int fb = fb_w + sl * 32;
        cb0[sl] = *(const f32x4*)(fcb + fb + hi * 4);
        cb1[sl] = *(const f32x4*)(fcb + fb + 16 + hi * 4);
    }

    // ---- synthesize U_pr^T A-fragments (carry coeff*scale/L) ---------------
    bfrag4 u00[2], u01[2], u10[2], u11[2];
    {
        const float scp = prs[0] * (1.0f / 8388608.0f);
        const int pp = lr & 1;
        #pragma unroll
        for (int rv = 0; rv < 2; ++rv) {         // rv=0: r2=lr, rv=1: r2=16+lr
            int kk = rv * 8 + (lr >> 1);
            bool kp = keep_coef(pidx, kk);
            unsigned s = (((unsigned)pidx[kk]) << 10) & LMASK;
            float a = kp ? prr[kk] * scp : 0.f;
            float b = kp ? pri[kk] * scp : 0.f;
            #pragma unroll
            for (int sl = 0; sl < 2; ++sl) {
                #pragma unroll
                for (int hf = 0; hf < 2; ++hf) {
                    unsigned f0 = (unsigned)(fb_w + sl * 32 + hf * 16 + 4 * hi);
                    float v[4];
                    #pragma unroll
                    for (int t = 0; t < 4; ++t) {
                        float sn, cs;
                        sc_ph((s * (f0 + t)) & LMASK, sn, cs);
                        v[t] = pp ? fmaf(a, sn, b * cs) : fmaf(a, cs, -b * sn);
                    }
                    uint2 pw = make_uint2(pk2bf(v[0], v[1]), pk2bf(v[2], v[3]));
                    bfrag4 fr = __builtin_bit_cast(bfrag4, pw);
                    if      (rv == 0 && hf == 0) u00[sl] = fr;
                    else if (rv == 0 && hf == 1) u01[sl] = fr;
                    else if (rv == 1 && hf == 0) u10[sl] = fr;
                    else                         u11[sl] = fr;
                }
            }
        }
    }
    const int toff = lr * 32 + hi * 8;

    #pragma unroll 1
    for (int pi = 0; pi < 8; ++pi) {
        int ga = g0 + pi * 2, gb = ga + 1;
        bfrag8 tA = *(const bfrag8*)(t1 + (size_t)ga * 512 + toff);
        bfrag8 tB = *(const bfrag8*)(t1 + (size_t)gb * 512 + toff);
        f32x4 aA0 = {0.f,0.f,0.f,0.f}, aA1 = {0.f,0.f,0.f,0.f};
        f32x4 aB0 = {0.f,0.f,0.f,0.f}, aB1 = {0.f,0.f,0.f,0.f};
        #pragma unroll
        for (int sl = 0; sl < 2; ++sl) {
            f32x4 sA0 = __builtin_amdgcn_mfma_f32_16x16x32_bf16(va0[sl], tA, cb0[sl], 0, 0, 0);
            f32x4 sB0 = __builtin_amdgcn_mfma_f32_16x16x32_bf16(va0[sl], tB, cb0[sl], 0, 0, 0);
            f32x4 sA1 = __builtin_amdgcn_mfma_f32_16x16x32_bf16(va1[sl], tA, cb1[sl], 0, 0, 0);
            f32x4 sB1 = __builtin_amdgcn_mfma_f32_16x16x32_bf16(va1[sl], tB, cb1[sl], 0, 0, 0);
            uint2 hA0 = make_uint2(pk2bf(gelu_fast(sA0[0]), gelu_fast(sA0[1])),
                                   pk2bf(gelu_fast(sA0[2]), gelu_fast(sA0[3])));
            uint2 hB0 = make_uint2(pk2bf(gelu_fast(sB0[0]), gelu_fast(sB0[1])),
                                   pk2bf(gelu_fast(sB0[2]), gelu_fast(sB0[3])));
            uint2 hA1 = make_uint2(pk2bf(gelu_fast(sA1[0]), gelu_fast(sA1[1])),
                                   pk2bf(gelu_fast(sA1[2]), gelu_fast(sA1[3])));
            uint2 hB1 = make_uint2(pk2bf(gelu_fast(sB1[0]), gelu_fast(sB1[1])),
                                   pk2bf(gelu_fast(sB1[2]), gelu_fast(sB1[3])));
            bfrag4 fA0 = __builtin_bit_cast(bfrag4, hA0);
            bfrag4 fB0 = __builtin_bit_cast(bfrag4, hB0);
            bfrag4 fA1 = __builtin_bit_cast(bfrag4, hA1);
            bfrag4 fB1 = __builtin_bit_cast(bfrag4, hB1);
            mfma16(aA0, u00[sl], fA0);
            mfma16(aB0, u00[sl], fB0);
            mfma16(aA1, u10[sl], fA0);
            mfma16(aB1, u10[sl], fB0);
            mfma16(aA0, u01[sl], fA1);
            mfma16(aB0, u01[sl], fB1);
            mfma16(aA1, u11[sl], fA1);
            mfma16(aB1, u11[sl], fB1);
        }
        // ---- cross-wave reduce for both groups (rotation swizzle) ----------
        #pragma unroll
        for (int r = 0; r < 4; ++r) {
            int r2a = hi * 4 + r, r2b = 16 + hi * 4 + r;
            red[(0 * 8 + w) * 512 + lr * 32 + ((r2a + lr) & 31)] = aA0[r];
            red[(0 * 8 + w) * 512 + lr * 32 + ((r2b + lr) & 31)] = aA1[r];
            red[(1 * 8 + w) * 512 + lr * 32 + ((r2a + lr) & 31)] = aB0[r];
            red[(1 * 8 + w) * 512 + lr * 32 + ((r2b + lr) & 31)] = aB1[r];
        }
        __syncthreads();
        {
            int tok = tid >> 5, rr = tid & 31;
            int slot = tok * 32 + ((rr + tok) & 31);
            float sa = 0.f, sb = 0.f;
            #pragma unroll
            for (int w2 = 0; w2 < 8; ++w2) {
                sa += red[(0 * 8 + w2) * 512 + slot];
                sb += red[(1 * 8 + w2) * 512 + slot];
            }
            t2p[((size_t)fc * 512 + ga) * 512 + tid] = f2bf(sa);   // [tok][r2]
            t2p[((size_t)fc * 512 + gb) * 512 + tid] = f2bf(sb);
        }
        __syncthreads();
    }
}

// ------ kernel 3: out = (sum_fc T2p) @ V_pr^T + b2  (512 blocks) ------------
__global__ __launch_bounds__(512, 4) void k_out(
    const unsigned short* __restrict__ t2p,      // [16][512 g][512] bf16
    const int* __restrict__ pidx,
    const float* __restrict__ prb,               // [2048]
    float* __restrict__ out)                     // [8192 tok][2048]
{
    __shared__ unsigned short lT[512];
    const int tid  = threadIdx.x;
    const int w    = tid >> 6;
    const int lane = tid & 63;
    const int lr   = lane & 15;
    const int hi   = lane >> 4;
    const int g    = blockIdx.x;
    const size_t tok0 = (size_t)g * 16;

    {
        float s = 0.f;
        #pragma unroll
        for (int c = 0; c < 16; ++c)
            s += bf2f(t2p[((size_t)c * 512 + g) * 512 + tid]);
        lT[tid] = f2bf(s);
    }
    unsigned skv[4];
    #pragma unroll
    for (int c = 0; c < 4; ++c) skv[c] = ((unsigned)pidx[hi * 4 + c]) & LMASK;
    __syncthreads();
    const bfrag8 t2a = *(const bfrag8*)(lT + lr * 32 + hi * 8);
    #pragma unroll 4
    for (int nj = 0; nj < 16; ++nj) {
        int d = w * 256 + nj * 16 + lr;
        unsigned m = ((unsigned)d) >> 1;
        int pd = d & 1;
        float v[8];
        #pragma unroll
        for (int c = 0; c < 4; ++c) {
            float sn, cs;
            sc_ph((skv[c] * m) & LMASK, sn, cs);
            v[2 * c]     = pd ? sn : cs;
            v[2 * c + 1] = pd ? cs : -sn;
        }
        uint4 pw = make_uint4(pk2bf(v[0], v[1]), pk2bf(v[2], v[3]),
                              pk2bf(v[4], v[5]), pk2bf(v[6], v[7]));
        bfrag8 vp = __builtin_bit_cast(bfrag8, pw);
        float bn = prb[d];
        f32x4 c4 = {bn, bn, bn, bn};
        f32x4 o = __builtin_amdgcn_mfma_f32_16x16x32_bf16(t2a, vp, c4, 0, 0, 0);
        #pragma unroll
        for (int r = 0; r < 4; ++r)
            out[(tok0 + hi * 4 + r) * 2048 + d] = o[r];
    }
}

// ---------------------------------------------------------------------------
extern "C" void kernel_launch(void* const* d_in, const int* in_sizes, int n_in,
                              void* d_out, int out_size, void* d_ws, size_t ws_size,
                              hipStream_t stream) {
    (void)in_sizes; (void)n_in; (void)out_size; (void)ws_size;
    const float* x   = (const float*)d_in[0];
    const float* fcr = (const float*)d_in[1];
    const float* fci = (const float*)d_in[2];
    const float* fcs = (const float*)d_in[3];
    const float* prr = (const float*)d_in[4];
    const float* pri = (const float*)d_in[5];
    const float* prs = (const float*)d_in[6];
    const float* fcb = (const float*)d_in[7];
    const float* prb = (const float*)d_in[8];
    const int* fidx  = (const int*)d_in[9];
    const int* pidx  = (const int*)d_in[10];
    float* out = (float*)d_out;
    char* ws = (char*)d_ws;

    size_t off = 0;
    auto take = [&](size_t bytes) { size_t p = off; off = (off + bytes + 255) & ~(size_t)255; return p; };
    unsigned short* t1  = (unsigned short*)(ws + take((size_t)8192 * 32 * 2));       // T1 [8192][32] bf16
    unsigned short* t2p = (unsigned short*)(ws + take((size_t)16 * 8192 * 32 * 2));  // T2 partials bf16

    k_t1 <<<dim3(512),    512, 0, stream>>>(x, fcr, fci, fidx, fcs, t1);
    k_mid<<<dim3(16, 32), 512, 0, stream>>>(t1, fidx, pidx, prr, pri, prs, fcb, t2p);
    k_out<<<dim3(512),    512, 0, stream>>>(t2p, pidx, prb, out);
}

// Round 10
// 69.949 us; speedup vs baseline: 1.0994x; 1.0994x over previous
//
#include <hip/hip_runtime.h>
#include <stdint.h>

// ---------------------------------------------------------------------------
// FastHelgasonLayer: weights are IFFTs of 16-sparse spectra => exactly rank-32.
//   W_fc = U_fc(2048x32)V_fc(32x8192), W_proj = U_pr(8192x32)V_pr(32x2048)
// Round 10: k_mid waves split TOKENS (not f) — each wave runs the whole 512-f
// chunk for its 2 token-groups, T2 f-sum happens inside the MFMA16 accumulator,
// cross-wave reduce + per-round barriers eliminated. Factors staged once in LDS.
// ---------------------------------------------------------------------------

typedef short bfrag8 __attribute__((ext_vector_type(8)));   // 8 bf16
typedef short bfrag4 __attribute__((ext_vector_type(4)));   // 4 bf16
typedef float f32x4  __attribute__((ext_vector_type(4)));

#define LMASK 8388607u      // 2^23 - 1
#define TWO_PI_OVER_L 7.4901405658478575e-7f

__device__ __forceinline__ unsigned short f2bf(float f) {
    unsigned u = __float_as_uint(f);
    u = (u + 0x7FFFu + ((u >> 16) & 1u)) >> 16;   // RTN-even
    return (unsigned short)u;
}
__device__ __forceinline__ float bf2f(unsigned short h) {
    unsigned u = ((unsigned)h) << 16;
    return __builtin_bit_cast(float, u);
}
__device__ __forceinline__ unsigned pk2bf(float a, float b) {
    unsigned ua = __float_as_uint(a) + 0x8000u;
    unsigned ub = __float_as_uint(b) + 0x8000u;
    return __builtin_amdgcn_perm(ub, ua, 0x07060302u);
}
__device__ __forceinline__ float gelu_fast(float x) {
    float xx = x * x;
    float p  = fmaf(xx, 0.044715f, 1.0f);
    float t  = (x * p) * -2.3022083f;             // -2*sqrt(2/pi)*log2(e)
    float e  = __builtin_amdgcn_exp2f(t);
    return x * __builtin_amdgcn_rcpf(1.0f + e);
}
__device__ __forceinline__ void sc_ph(unsigned ph, float& sn, float& cs) {
    __sincosf((float)ph * TWO_PI_OVER_L, &sn, &cs);
}

#if defined(__has_builtin)
#if __has_builtin(__builtin_amdgcn_mfma_f32_16x16x16bf16_1k)
#define HAVE_MFMA16_1K 1
#endif
#endif
__device__ __forceinline__ void mfma16(f32x4& acc, bfrag4 a, bfrag4 b) {
#ifdef HAVE_MFMA16_1K
    acc = __builtin_amdgcn_mfma_f32_16x16x16bf16_1k(a, b, acc, 0, 0, 0);
#else
    asm("v_mfma_f32_16x16x16_bf16 %0, %1, %2, %0" : "+v"(acc) : "v"(a), "v"(b));
#endif
}

// dedup (last-write-wins): coeff kk survives only if no later j has same index
__device__ __forceinline__ bool keep_coef(const int* __restrict__ idx, int kk) {
    int v = idx[kk];
    bool keep = true;
    for (int j = kk + 1; j < 16; ++j) keep = keep && (idx[j] != v);
    return keep;
}

// ------------------ kernel 1: T1 = x @ U_fc  (512 blocks, r9-verified) ------
__global__ __launch_bounds__(512, 4) void k_t1(
    const float* __restrict__ x,                 // [8192 tok][2048]
    const float* __restrict__ fcr, const float* __restrict__ fci,
    const int* __restrict__ fidx,  const float* __restrict__ fcs,
    unsigned short* __restrict__ t1)             // [512 g][16 tok][32 r] bf16
{
    __shared__ float red[8 * 512];
    const int tid  = threadIdx.x;
    const int w    = tid >> 6;
    const int lane = tid & 63;
    const int lr   = lane & 15;
    const int hi   = lane >> 4;
    const size_t tok0 = (size_t)blockIdx.x * 16;

    const float sc = fcs[0] * (1.0f / 8388608.0f);
    const int p   = lr & 1;
    const int kk0 = lr >> 1, kk1 = 8 + (lr >> 1);
    unsigned s0, s1; float a0, b0, a1, b1;
    {
        bool k0 = keep_coef(fidx, kk0), k1 = keep_coef(fidx, kk1);
        s0 = (((unsigned)fidx[kk0]) << 12) & LMASK;
        s1 = (((unsigned)fidx[kk1]) << 12) & LMASK;
        a0 = k0 ? fcr[kk0] * sc : 0.f;  b0 = k0 ? fci[kk0] * sc : 0.f;
        a1 = k1 ? fcr[kk1] * sc : 0.f;  b1 = k1 ? fci[kk1] * sc : 0.f;
    }

    f32x4 acc[2];
    { f32x4 z = {0.f,0.f,0.f,0.f}; acc[0] = z; acc[1] = z; }
    #pragma unroll 2
    for (int s = 0; s < 8; ++s) {
        int k = w * 256 + s * 32 + hi * 8;
        const float* xp = x + (tok0 + lr) * 2048 + k;
        float4 v0 = *(const float4*)xp;
        float4 v1 = *(const float4*)(xp + 4);
        uint4 aw = make_uint4(pk2bf(v0.x, v0.y), pk2bf(v0.z, v0.w),
                              pk2bf(v1.x, v1.y), pk2bf(v1.z, v1.w));
        bfrag8 af = __builtin_bit_cast(bfrag8, aw);
        float e0[8], e1[8];
        #pragma unroll
        for (int t = 0; t < 8; ++t) {
            float sn, cs;
            sc_ph((s0 * (unsigned)(k + t)) & LMASK, sn, cs);
            e0[t] = p ? fmaf(a0, sn, b0 * cs) : fmaf(a0, cs, -b0 * sn);
            sc_ph((s1 * (unsigned)(k + t)) & LMASK, sn, cs);
            e1[t] = p ? fmaf(a1, sn, b1 * cs) : fmaf(a1, cs, -b1 * sn);
        }
        uint4 bw0 = make_uint4(pk2bf(e0[0], e0[1]), pk2bf(e0[2], e0[3]),
                               pk2bf(e0[4], e0[5]), pk2bf(e0[6], e0[7]));
        uint4 bw1 = make_uint4(pk2bf(e1[0], e1[1]), pk2bf(e1[2], e1[3]),
                               pk2bf(e1[4], e1[5]), pk2bf(e1[6], e1[7]));
        bfrag8 bf0 = __builtin_bit_cast(bfrag8, bw0);
        bfrag8 bf1 = __builtin_bit_cast(bfrag8, bw1);
        acc[0] = __builtin_amdgcn_mfma_f32_16x16x32_bf16(af, bf0, acc[0], 0, 0, 0);
        acc[1] = __builtin_amdgcn_mfma_f32_16x16x32_bf16(af, bf1, acc[1], 0, 0, 0);
    }
    #pragma unroll
    for (int nj = 0; nj < 2; ++nj)      // C: row=tok(4hi+r), col=r(nj*16+lr)
        #pragma unroll
        for (int r = 0; r < 4; ++r)
            red[w * 512 + (hi * 4 + r) * 32 + nj * 16 + lr] = acc[nj][r];
    __syncthreads();
    float s = 0.f;
    #pragma unroll
    for (int w2 = 0; w2 < 8; ++w2) s += red[w2 * 512 + tid];
    t1[(size_t)blockIdx.x * 512 + tid] = f2bf(s);
}

// -------- kernel 2: middle loop — waves own TOKENS, f-sum in accumulator ----
// block = one 512-f chunk; factors staged in LDS once; 32-iter barrier-free
// loop per wave; each wave computes T2 for its 2 token-groups fully.
__global__ __launch_bounds__(512, 2) void k_mid(
    const unsigned short* __restrict__ t1,       // [512 g][512]
    const int* __restrict__ fidx,
    const int* __restrict__ pidx,
    const float* __restrict__ prr, const float* __restrict__ pri,
    const float* __restrict__ prs,
    const float* __restrict__ fcb,               // [8192]
    unsigned short* __restrict__ t2p)            // [16 fc][512 g][512] bf16
{
    __shared__ __align__(16) unsigned short vfc[512 * 32];   // 32 KB [f_l][32 r]
    __shared__ __align__(16) unsigned short upr[32 * 520];   // 33.3 KB [r2][520]
    __shared__ float lbias[512];                             // 2 KB
    const int tid  = threadIdx.x;
    const int w    = tid >> 6;
    const int lane = tid & 63;
    const int lr   = lane & 15;
    const int hi   = lane >> 4;
    const int fc   = blockIdx.x;            // f-chunk 0..15 (512 f each)

    // ---- stage V_fc^T rows: thread t -> f_local t (16 sincos) --------------
    {
        int jg = fc * 512 + tid;
        unsigned m = ((unsigned)jg) >> 1;
        int pj = jg & 1;
        unsigned short* row = vfc + tid * 32;
        #pragma unroll
        for (int k = 0; k < 16; ++k) {
            float sn, cs;
            sc_ph(((((unsigned)fidx[k]) & LMASK) * m) & LMASK, sn, cs);
            row[2 * k]     = f2bf(pj ? sn : cs);
            row[2 * k + 1] = f2bf(pj ? cs : -sn);
        }
    }
    // ---- stage U_pr^T rows: thread t -> (k = t>>5, 16 f) (16 sincos) -------
    {
        const float scp = prs[0] * (1.0f / 8388608.0f);
        int k  = tid >> 5;
        int f0 = (tid & 31) * 16;
        bool kp = keep_coef(pidx, k);
        unsigned s = (((unsigned)pidx[k]) << 10) & LMASK;
        float a = kp ? prr[k] * scp : 0.f;
        float b = kp ? pri[k] * scp : 0.f;
        unsigned short* r0 = upr + (2 * k) * 520 + f0;
        unsigned short* r1 = upr + (2 * k + 1) * 520 + f0;
        unsigned fg = (unsigned)(fc * 512 + f0);
        #pragma unroll
        for (int t = 0; t < 16; ++t) {
            float sn, cs;
            sc_ph((s * (fg + t)) & LMASK, sn, cs);
            r0[t] = f2bf(fmaf(a, cs, -b * sn));
            r1[t] = f2bf(fmaf(a, sn, b * cs));
        }
    }
    lbias[tid] = fcb[fc * 512 + tid];
    __syncthreads();

    // ---- per-wave: 2 token-groups, full 512-f accumulation, no barriers ----
    const int ga = blockIdx.y * 16 + w * 2, gb = ga + 1;
    const int toff = lr * 32 + hi * 8;
    const bfrag8 tA = *(const bfrag8*)(t1 + (size_t)ga * 512 + toff);
    const bfrag8 tB = *(const bfrag8*)(t1 + (size_t)gb * 512 + toff);
    f32x4 aA0 = {0.f,0.f,0.f,0.f}, aA1 = {0.f,0.f,0.f,0.f};
    f32x4 aB0 = {0.f,0.f,0.f,0.f}, aB1 = {0.f,0.f,0.f,0.f};

    #pragma unroll 2
    for (int it = 0; it < 32; ++it) {
        const int f0 = it * 16;
        // S^T = Vfc(16f x 32r) @ T1^T(32r x 16tok) + bias; row=f(4hi+r), col=tok(lr)
        bfrag8 va = *(const bfrag8*)(vfc + (f0 + lr) * 32 + hi * 8);
        f32x4 cbv = *(const f32x4*)(lbias + f0 + hi * 4);      // broadcast read
        f32x4 sA = __builtin_amdgcn_mfma_f32_16x16x32_bf16(va, tA, cbv, 0, 0, 0);
        f32x4 sB = __builtin_amdgcn_mfma_f32_16x16x32_bf16(va, tB, cbv, 0, 0, 0);
        // gelu + pack: C-layout == B-frag of K=16 MFMA (k=f, col=tok)
        uint2 hwA = make_uint2(pk2bf(gelu_fast(sA[0]), gelu_fast(sA[1])),
                               pk2bf(gelu_fast(sA[2]), gelu_fast(sA[3])));
        uint2 hwB = make_uint2(pk2bf(gelu_fast(sB[0]), gelu_fast(sB[1])),
                               pk2bf(gelu_fast(sB[2]), gelu_fast(sB[3])));
        bfrag4 hA = __builtin_bit_cast(bfrag4, hwA);
        bfrag4 hB = __builtin_bit_cast(bfrag4, hwB);
        // U_pr^T A-frags: row=r2(lr | 16+lr), k=f(4hi+j); padded rows => <=2-way
        bfrag4 u0 = *(const bfrag4*)(upr + lr * 520 + f0 + hi * 4);
        bfrag4 u1 = *(const bfrag4*)(upr + (16 + lr) * 520 + f0 + hi * 4);
        // T2^T += U_pr^T(16r2 x 16f) * hT(16f x 16tok): f-sum in accumulator
        mfma16(aA0, u0, hA);
        mfma16(aA1, u1, hA);
        mfma16(aB0, u0, hB);
        mfma16(aB1, u1, hB);
    }

    // ---- direct t2p writes (lane holds r2 = 4hi+r [+16], tok = lr) ---------
    {
        unsigned short* oa = t2p + ((size_t)fc * 512 + ga) * 512;
        unsigned short* ob = t2p + ((size_t)fc * 512 + gb) * 512;
        *(uint2*)(oa + lr * 32 + hi * 4)      = make_uint2(pk2bf(aA0[0], aA0[1]), pk2bf(aA0[2], aA0[3]));
        *(uint2*)(oa + lr * 32 + 16 + hi * 4) = make_uint2(pk2bf(aA1[0], aA1[1]), pk2bf(aA1[2], aA1[3]));
        *(uint2*)(ob + lr * 32 + hi * 4)      = make_uint2(pk2bf(aB0[0], aB0[1]), pk2bf(aB0[2], aB0[3]));
        *(uint2*)(ob + lr * 32 + 16 + hi * 4) = make_uint2(pk2bf(aB1[0], aB1[1]), pk2bf(aB1[2], aB1[3]));
    }
}

// ------ kernel 3: out = (sum_fc T2p) @ V_pr^T + b2  (512 blocks, r9) --------
__global__ __launch_bounds__(512, 4) void k_out(
    const unsigned short* __restrict__ t2p,      // [16][512 g][512] bf16
    const int* __restrict__ pidx,
    const float* __restrict__ prb,               // [2048]
    float* __restrict__ out)                     // [8192 tok][2048]
{
    __shared__ unsigned short lT[512];
    const int tid  = threadIdx.x;
    const int w    = tid >> 6;
    const int lane = tid & 63;
    const int lr   = lane & 15;
    const int hi   = lane >> 4;
    const int g    = blockIdx.x;
    const size_t tok0 = (size_t)g * 16;

    {
        float s = 0.f;
        #pragma unroll
        for (int c = 0; c < 16; ++c)
            s += bf2f(t2p[((size_t)c * 512 + g) * 512 + tid]);
        lT[tid] = f2bf(s);
    }
    unsigned skv[4];
    #pragma unroll
    for (int c = 0; c < 4; ++c) skv[c] = ((unsigned)pidx[hi * 4 + c]) & LMASK;
    __syncthreads();
    const bfrag8 t2a = *(const bfrag8*)(lT + lr * 32 + hi * 8);
    #pragma unroll 4
    for (int nj = 0; nj < 16; ++nj) {
        int d = w * 256 + nj * 16 + lr;
        unsigned m = ((unsigned)d) >> 1;
        int pd = d & 1;
        float v[8];
        #pragma unroll
        for (int c = 0; c < 4; ++c) {
            float sn, cs;
            sc_ph((skv[c] * m) & LMASK, sn, cs);
            v[2 * c]     = pd ? sn : cs;
            v[2 * c + 1] = pd ? cs : -sn;
        }
        uint4 pw = make_uint4(pk2bf(v[0], v[1]), pk2bf(v[2], v[3]),
                              pk2bf(v[4], v[5]), pk2bf(v[6], v[7]));
        bfrag8 vp = __builtin_bit_cast(bfrag8, pw);
        float bn = prb[d];
        f32x4 c4 = {bn, bn, bn, bn};
        f32x4 o = __builtin_amdgcn_mfma_f32_16x16x32_bf16(t2a, vp, c4, 0, 0, 0);
        #pragma unroll
        for (int r = 0; r < 4; ++r)
            out[(tok0 + hi * 4 + r) * 2048 + d] = o[r];
    }
}

// ---------------------------------------------------------------------------
extern "C" void kernel_launch(void* const* d_in, const int* in_sizes, int n_in,
                              void* d_out, int out_size, void* d_ws, size_t ws_size,
                              hipStream_t stream) {
    (void)in_sizes; (void)n_in; (void)out_size; (void)ws_size;
    const float* x   = (const float*)d_in[0];
    const float* fcr = (const float*)d_in[1];
    const float* fci = (const float*)d_in[2];
    const float* fcs = (const float*)d_in[3];
    const float* prr = (const float*)d_in[4];
    const float* pri = (const float*)d_in[5];
    const float* prs = (const float*)d_in[6];
    const float* fcb = (const float*)d_in[7];
    const float* prb = (const float*)d_in[8];
    const int* fidx  = (const int*)d_in[9];
    const int* pidx  = (const int*)d_in[10];
    float* out = (float*)d_out;
    char* ws = (char*)d_ws;

    size_t off = 0;
    auto take = [&](size_t bytes) { size_t p = off; off = (off + bytes + 255) & ~(size_t)255; return p; };
    unsigned short* t1  = (unsigned short*)(ws + take((size_t)8192 * 32 * 2));       // T1 [8192][32] bf16
    unsigned short* t2p = (unsigned short*)(ws + take((size_t)16 * 8192 * 32 * 2));  // T2 partials bf16

    k_t1 <<<dim3(512),    512, 0, stream>>>(x, fcr, fci, fidx, fcs, t1);
    k_mid<<<dim3(16, 32), 512, 0, stream>>>(t1, fidx, pidx, prr, pri, prs, fcb, t2p);
    k_out<<<dim3(512),    512, 0, stream>>>(t2p, pidx, prb, out);
}

// Round 11
// 69.121 us; speedup vs baseline: 1.1126x; 1.0120x over previous
//
#include <hip/hip_runtime.h>
#include <stdint.h>

// ---------------------------------------------------------------------------
// FastHelgasonLayer: weights are IFFTs of 16-sparse spectra => exactly rank-32.
//   W_fc = U_fc(2048x32)V_fc(32x8192), W_proj = U_pr(8192x32)V_pr(32x2048)
// Round 11: k_mid fixes — vfc padded to 40-elem rows (8-way -> 2-way banks),
// 32 f per iteration with per-half accumulators (4 independent chains/wave).
// ---------------------------------------------------------------------------

typedef short bfrag8 __attribute__((ext_vector_type(8)));   // 8 bf16
typedef short bfrag4 __attribute__((ext_vector_type(4)));   // 4 bf16
typedef float f32x4  __attribute__((ext_vector_type(4)));

#define LMASK 8388607u      // 2^23 - 1
#define TWO_PI_OVER_L 7.4901405658478575e-7f

__device__ __forceinline__ unsigned short f2bf(float f) {
    unsigned u = __float_as_uint(f);
    u = (u + 0x7FFFu + ((u >> 16) & 1u)) >> 16;   // RTN-even
    return (unsigned short)u;
}
__device__ __forceinline__ float bf2f(unsigned short h) {
    unsigned u = ((unsigned)h) << 16;
    return __builtin_bit_cast(float, u);
}
__device__ __forceinline__ unsigned pk2bf(float a, float b) {
    unsigned ua = __float_as_uint(a) + 0x8000u;
    unsigned ub = __float_as_uint(b) + 0x8000u;
    return __builtin_amdgcn_perm(ub, ua, 0x07060302u);
}
__device__ __forceinline__ float gelu_fast(float x) {
    float xx = x * x;
    float p  = fmaf(xx, 0.044715f, 1.0f);
    float t  = (x * p) * -2.3022083f;             // -2*sqrt(2/pi)*log2(e)
    float e  = __builtin_amdgcn_exp2f(t);
    return x * __builtin_amdgcn_rcpf(1.0f + e);
}
__device__ __forceinline__ void sc_ph(unsigned ph, float& sn, float& cs) {
    __sincosf((float)ph * TWO_PI_OVER_L, &sn, &cs);
}

#if defined(__has_builtin)
#if __has_builtin(__builtin_amdgcn_mfma_f32_16x16x16bf16_1k)
#define HAVE_MFMA16_1K 1
#endif
#endif
__device__ __forceinline__ void mfma16(f32x4& acc, bfrag4 a, bfrag4 b) {
#ifdef HAVE_MFMA16_1K
    acc = __builtin_amdgcn_mfma_f32_16x16x16bf16_1k(a, b, acc, 0, 0, 0);
#else
    asm("v_mfma_f32_16x16x16_bf16 %0, %1, %2, %0" : "+v"(acc) : "v"(a), "v"(b));
#endif
}

// dedup (last-write-wins): coeff kk survives only if no later j has same index
__device__ __forceinline__ bool keep_coef(const int* __restrict__ idx, int kk) {
    int v = idx[kk];
    bool keep = true;
    for (int j = kk + 1; j < 16; ++j) keep = keep && (idx[j] != v);
    return keep;
}

// ------------------ kernel 1: T1 = x @ U_fc  (512 blocks, r9-verified) ------
__global__ __launch_bounds__(512, 4) void k_t1(
    const float* __restrict__ x,                 // [8192 tok][2048]
    const float* __restrict__ fcr, const float* __restrict__ fci,
    const int* __restrict__ fidx,  const float* __restrict__ fcs,
    unsigned short* __restrict__ t1)             // [512 g][16 tok][32 r] bf16
{
    __shared__ float red[8 * 512];
    const int tid  = threadIdx.x;
    const int w    = tid >> 6;
    const int lane = tid & 63;
    const int lr   = lane & 15;
    const int hi   = lane >> 4;
    const size_t tok0 = (size_t)blockIdx.x * 16;

    const float sc = fcs[0] * (1.0f / 8388608.0f);
    const int p   = lr & 1;
    const int kk0 = lr >> 1, kk1 = 8 + (lr >> 1);
    unsigned s0, s1; float a0, b0, a1, b1;
    {
        bool k0 = keep_coef(fidx, kk0), k1 = keep_coef(fidx, kk1);
        s0 = (((unsigned)fidx[kk0]) << 12) & LMASK;
        s1 = (((unsigned)fidx[kk1]) << 12) & LMASK;
        a0 = k0 ? fcr[kk0] * sc : 0.f;  b0 = k0 ? fci[kk0] * sc : 0.f;
        a1 = k1 ? fcr[kk1] * sc : 0.f;  b1 = k1 ? fci[kk1] * sc : 0.f;
    }

    f32x4 acc[2];
    { f32x4 z = {0.f,0.f,0.f,0.f}; acc[0] = z; acc[1] = z; }
    #pragma unroll 2
    for (int s = 0; s < 8; ++s) {
        int k = w * 256 + s * 32 + hi * 8;
        const float* xp = x + (tok0 + lr) * 2048 + k;
        float4 v0 = *(const float4*)xp;
        float4 v1 = *(const float4*)(xp + 4);
        uint4 aw = make_uint4(pk2bf(v0.x, v0.y), pk2bf(v0.z, v0.w),
                              pk2bf(v1.x, v1.y), pk2bf(v1.z, v1.w));
        bfrag8 af = __builtin_bit_cast(bfrag8, aw);
        float e0[8], e1[8];
        #pragma unroll
        for (int t = 0; t < 8; ++t) {
            float sn, cs;
            sc_ph((s0 * (unsigned)(k + t)) & LMASK, sn, cs);
            e0[t] = p ? fmaf(a0, sn, b0 * cs) : fmaf(a0, cs, -b0 * sn);
            sc_ph((s1 * (unsigned)(k + t)) & LMASK, sn, cs);
            e1[t] = p ? fmaf(a1, sn, b1 * cs) : fmaf(a1, cs, -b1 * sn);
        }
        uint4 bw0 = make_uint4(pk2bf(e0[0], e0[1]), pk2bf(e0[2], e0[3]),
                               pk2bf(e0[4], e0[5]), pk2bf(e0[6], e0[7]));
        uint4 bw1 = make_uint4(pk2bf(e1[0], e1[1]), pk2bf(e1[2], e1[3]),
                               pk2bf(e1[4], e1[5]), pk2bf(e1[6], e1[7]));
        bfrag8 bf0 = __builtin_bit_cast(bfrag8, bw0);
        bfrag8 bf1 = __builtin_bit_cast(bfrag8, bw1);
        acc[0] = __builtin_amdgcn_mfma_f32_16x16x32_bf16(af, bf0, acc[0], 0, 0, 0);
        acc[1] = __builtin_amdgcn_mfma_f32_16x16x32_bf16(af, bf1, acc[1], 0, 0, 0);
    }
    #pragma unroll
    for (int nj = 0; nj < 2; ++nj)      // C: row=tok(4hi+r), col=r(nj*16+lr)
        #pragma unroll
        for (int r = 0; r < 4; ++r)
            red[w * 512 + (hi * 4 + r) * 32 + nj * 16 + lr] = acc[nj][r];
    __syncthreads();
    float s = 0.f;
    #pragma unroll
    for (int w2 = 0; w2 < 8; ++w2) s += red[w2 * 512 + tid];
    t1[(size_t)blockIdx.x * 512 + tid] = f2bf(s);
}

// -------- kernel 2: middle loop — tokens split across waves, 32 f / iter ----
// vfc rows padded to 40 elems (<=2-way banks); per-half accumulators give 4
// independent MFMA/gelu chains per wave-iteration; no barriers in the loop.
__global__ __launch_bounds__(512, 4) void k_mid(
    const unsigned short* __restrict__ t1,       // [512 g][512]
    const int* __restrict__ fidx,
    const int* __restrict__ pidx,
    const float* __restrict__ prr, const float* __restrict__ pri,
    const float* __restrict__ prs,
    const float* __restrict__ fcb,               // [8192]
    unsigned short* __restrict__ t2p)            // [16 fc][512 g][512] bf16
{
    __shared__ __align__(16) unsigned short vfc[512 * 40];   // 40 KB [f_l][40]
    __shared__ __align__(16) unsigned short upr[32 * 520];   // 33.3 KB [r2][520]
    __shared__ float lbias[512];                             // 2 KB
    const int tid  = threadIdx.x;
    const int w    = tid >> 6;
    const int lane = tid & 63;
    const int lr   = lane & 15;
    const int hi   = lane >> 4;
    const int fc   = blockIdx.x;            // f-chunk 0..15 (512 f each)

    // ---- stage V_fc^T rows: thread t -> f_local t (16 sincos) --------------
    {
        int jg = fc * 512 + tid;
        unsigned m = ((unsigned)jg) >> 1;
        int pj = jg & 1;
        unsigned short* row = vfc + tid * 40;
        #pragma unroll
        for (int k = 0; k < 16; ++k) {
            float sn, cs;
            sc_ph(((((unsigned)fidx[k]) & LMASK) * m) & LMASK, sn, cs);
            row[2 * k]     = f2bf(pj ? sn : cs);
            row[2 * k + 1] = f2bf(pj ? cs : -sn);
        }
    }
    // ---- stage U_pr^T rows: thread t -> (k = t>>5, 16 f) (16 sincos) -------
    {
        const float scp = prs[0] * (1.0f / 8388608.0f);
        int k  = tid >> 5;
        int f0 = (tid & 31) * 16;
        bool kp = keep_coef(pidx, k);
        unsigned s = (((unsigned)pidx[k]) << 10) & LMASK;
        float a = kp ? prr[k] * scp : 0.f;
        float b = kp ? pri[k] * scp : 0.f;
        unsigned short* r0 = upr + (2 * k) * 520 + f0;
        unsigned short* r1 = upr + (2 * k + 1) * 520 + f0;
        unsigned fg = (unsigned)(fc * 512 + f0);
        #pragma unroll
        for (int t = 0; t < 16; ++t) {
            float sn, cs;
            sc_ph((s * (fg + t)) & LMASK, sn, cs);
            r0[t] = f2bf(fmaf(a, cs, -b * sn));
            r1[t] = f2bf(fmaf(a, sn, b * cs));
        }
    }
    lbias[tid] = fcb[fc * 512 + tid];
    __syncthreads();

    // ---- per-wave: 2 token-groups, 16 iters x 32 f, no barriers ------------
    const int ga = blockIdx.y * 16 + w * 2, gb = ga + 1;
    const int toff = lr * 32 + hi * 8;
    const bfrag8 tA = *(const bfrag8*)(t1 + (size_t)ga * 512 + toff);
    const bfrag8 tB = *(const bfrag8*)(t1 + (size_t)gb * 512 + toff);
    f32x4 aA0[2], aA1[2], aB0[2], aB1[2];      // [half]
    #pragma unroll
    for (int h = 0; h < 2; ++h) {
        f32x4 z = {0.f,0.f,0.f,0.f};
        aA0[h] = z; aA1[h] = z; aB0[h] = z; aB1[h] = z;
    }

    #pragma unroll 2
    for (int it = 0; it < 16; ++it) {
        const int f0 = it * 32;
        // operands for both 16-f halves (padded vfc: <=2-way banks)
        bfrag8 va0 = *(const bfrag8*)(vfc + (f0 + lr) * 40 + hi * 8);
        bfrag8 va1 = *(const bfrag8*)(vfc + (f0 + 16 + lr) * 40 + hi * 8);
        f32x4 cb0 = *(const f32x4*)(lbias + f0 + hi * 4);
        f32x4 cb1 = *(const f32x4*)(lbias + f0 + 16 + hi * 4);
        bfrag4 u00 = *(const bfrag4*)(upr + lr * 520 + f0 + hi * 4);
        bfrag4 u10 = *(const bfrag4*)(upr + (16 + lr) * 520 + f0 + hi * 4);
        bfrag4 u01 = *(const bfrag4*)(upr + lr * 520 + f0 + 16 + hi * 4);
        bfrag4 u11 = *(const bfrag4*)(upr + (16 + lr) * 520 + f0 + 16 + hi * 4);
        // S tiles: 4 independent chains (group x half)
        f32x4 sA0 = __builtin_amdgcn_mfma_f32_16x16x32_bf16(va0, tA, cb0, 0, 0, 0);
        f32x4 sB0 = __builtin_amdgcn_mfma_f32_16x16x32_bf16(va0, tB, cb0, 0, 0, 0);
        f32x4 sA1 = __builtin_amdgcn_mfma_f32_16x16x32_bf16(va1, tA, cb1, 0, 0, 0);
        f32x4 sB1 = __builtin_amdgcn_mfma_f32_16x16x32_bf16(va1, tB, cb1, 0, 0, 0);
        // gelu + pack (C-layout == K=16 B-frag)
        uint2 hA0 = make_uint2(pk2bf(gelu_fast(sA0[0]), gelu_fast(sA0[1])),
                               pk2bf(gelu_fast(sA0[2]), gelu_fast(sA0[3])));
        uint2 hB0 = make_uint2(pk2bf(gelu_fast(sB0[0]), gelu_fast(sB0[1])),
                               pk2bf(gelu_fast(sB0[2]), gelu_fast(sB0[3])));
        uint2 hA1 = make_uint2(pk2bf(gelu_fast(sA1[0]), gelu_fast(sA1[1])),
                               pk2bf(gelu_fast(sA1[2]), gelu_fast(sA1[3])));
        uint2 hB1 = make_uint2(pk2bf(gelu_fast(sB1[0]), gelu_fast(sB1[1])),
                               pk2bf(gelu_fast(sB1[2]), gelu_fast(sB1[3])));
        bfrag4 fA0 = __builtin_bit_cast(bfrag4, hA0);
        bfrag4 fB0 = __builtin_bit_cast(bfrag4, hB0);
        bfrag4 fA1 = __builtin_bit_cast(bfrag4, hA1);
        bfrag4 fB1 = __builtin_bit_cast(bfrag4, hB1);
        // T2 accumulate: 8 MFMA16 into 8 distinct accumulators (no chains)
        mfma16(aA0[0], u00, fA0);
        mfma16(aA1[0], u10, fA0);
        mfma16(aB0[0], u00, fB0);
        mfma16(aB1[0], u10, fB0);
        mfma16(aA0[1], u01, fA1);
        mfma16(aA1[1], u11, fA1);
        mfma16(aB0[1], u01, fB1);
        mfma16(aB1[1], u11, fB1);
    }
    // merge halves
    f32x4 vA0 = aA0[0] + aA0[1], vA1 = aA1[0] + aA1[1];
    f32x4 vB0 = aB0[0] + aB0[1], vB1 = aB1[0] + aB1[1];

    // ---- direct t2p writes (lane holds r2 = 4hi+r [+16], tok = lr) ---------
    {
        unsigned short* oa = t2p + ((size_t)fc * 512 + ga) * 512;
        unsigned short* ob = t2p + ((size_t)fc * 512 + gb) * 512;
        *(uint2*)(oa + lr * 32 + hi * 4)      = make_uint2(pk2bf(vA0[0], vA0[1]), pk2bf(vA0[2], vA0[3]));
        *(uint2*)(oa + lr * 32 + 16 + hi * 4) = make_uint2(pk2bf(vA1[0], vA1[1]), pk2bf(vA1[2], vA1[3]));
        *(uint2*)(ob + lr * 32 + hi * 4)      = make_uint2(pk2bf(vB0[0], vB0[1]), pk2bf(vB0[2], vB0[3]));
        *(uint2*)(ob + lr * 32 + 16 + hi * 4) = make_uint2(pk2bf(vB1[0], vB1[1]), pk2bf(vB1[2], vB1[3]));
    }
}

// ------ kernel 3: out = (sum_fc T2p) @ V_pr^T + b2  (512 blocks, r9) --------
__global__ __launch_bounds__(512, 4) void k_out(
    const unsigned short* __restrict__ t2p,      // [16][512 g][512] bf16
    const int* __restrict__ pidx,
    const float* __restrict__ prb,               // [2048]
    float* __restrict__ out)                     // [8192 tok][2048]
{
    __shared__ unsigned short lT[512];
    const int tid  = threadIdx.x;
    const int w    = tid >> 6;
    const int lane = tid & 63;
    const int lr   = lane & 15;
    const int hi   = lane >> 4;
    const int g    = blockIdx.x;
    const size_t tok0 = (size_t)g * 16;

    {
        float s = 0.f;
        #pragma unroll
        for (int c = 0; c < 16; ++c)
            s += bf2f(t2p[((size_t)c * 512 + g) * 512 + tid]);
        lT[tid] = f2bf(s);
    }
    unsigned skv[4];
    #pragma unroll
    for (int c = 0; c < 4; ++c) skv[c] = ((unsigned)pidx[hi * 4 + c]) & LMASK;
    __syncthreads();
    const bfrag8 t2a = *(const bfrag8*)(lT + lr * 32 + hi * 8);
    #pragma unroll 4
    for (int nj = 0; nj < 16; ++nj) {
        int d = w * 256 + nj * 16 + lr;
        unsigned m = ((unsigned)d) >> 1;
        int pd = d & 1;
        float v[8];
        #pragma unroll
        for (int c = 0; c < 4; ++c) {
            float sn, cs;
            sc_ph((skv[c] * m) & LMASK, sn, cs);
            v[2 * c]     = pd ? sn : cs;
            v[2 * c + 1] = pd ? cs : -sn;
        }
        uint4 pw = make_uint4(pk2bf(v[0], v[1]), pk2bf(v[2], v[3]),
                              pk2bf(v[4], v[5]), pk2bf(v[6], v[7]));
        bfrag8 vp = __builtin_bit_cast(bfrag8, pw);
        float bn = prb[d];
        f32x4 c4 = {bn, bn, bn, bn};
        f32x4 o = __builtin_amdgcn_mfma_f32_16x16x32_bf16(t2a, vp, c4, 0, 0, 0);
        #pragma unroll
        for (int r = 0; r < 4; ++r)
            out[(tok0 + hi * 4 + r) * 2048 + d] = o[r];
    }
}

// ---------------------------------------------------------------------------
extern "C" void kernel_launch(void* const* d_in, const int* in_sizes, int n_in,
                              void* d_out, int out_size, void* d_ws, size_t ws_size,
                              hipStream_t stream) {
    (void)in_sizes; (void)n_in; (void)out_size; (void)ws_size;
    const float* x   = (const float*)d_in[0];
    const float* fcr = (const float*)d_in[1];
    const float* fci = (const float*)d_in[2];
    const float* fcs = (const float*)d_in[3];
    const float* prr = (const float*)d_in[4];
    const float* pri = (const float*)d_in[5];
    const float* prs = (const float*)d_in[6];
    const float* fcb = (const float*)d_in[7];
    const float* prb = (const float*)d_in[8];
    const int* fidx  = (const int*)d_in[9];
    const int* pidx  = (const int*)d_in[10];
    float* out = (float*)d_out;
    char* ws = (char*)d_ws;

    size_t off = 0;
    auto take = [&](size_t bytes) { size_t p = off; off = (off + bytes + 255) & ~(size_t)255; return p; };
    unsigned short* t1  = (unsigned short*)(ws + take((size_t)8192 * 32 * 2));       // T1 [8192][32] bf16
    unsigned short* t2p = (unsigned short*)(ws + take((size_t)16 * 8192 * 32 * 2));  // T2 partials bf16

    k_t1 <<<dim3(512),    512, 0, stream>>>(x, fcr, fci, fidx, fcs, t1);
    k_mid<<<dim3(16, 32), 512, 0, stream>>>(t1, fidx, pidx, prr, pri, prs, fcb, t2p);
    k_out<<<dim3(512),    512, 0, stream>>>(t2p, pidx, prb, out);
}

// Round 13
// 62.801 us; speedup vs baseline: 1.2246x; 1.1006x over previous
//
#include <hip/hip_runtime.h>
#include <stdint.h>

// ---------------------------------------------------------------------------
// FastHelgasonLayer: weights are IFFTs of 16-sparse spectra => exactly rank-32.
//   W_fc = U_fc(2048x32)V_fc(32x8192), W_proj = U_pr(8192x32)V_pr(32x2048)
// Round 13: r11 base (verified) + slim gelu + rotation chains in k_t1/k_out.
// NO inline-asm cvt_pk (r12's NaN bisect: packing stays on verified pk2bf).
// ---------------------------------------------------------------------------

typedef short bfrag8 __attribute__((ext_vector_type(8)));   // 8 bf16
typedef short bfrag4 __attribute__((ext_vector_type(4)));   // 4 bf16
typedef float f32x4  __attribute__((ext_vector_type(4)));

#define LMASK 8388607u      // 2^23 - 1
#define TWO_PI_OVER_L 7.4901405658478575e-7f

__device__ __forceinline__ unsigned short f2bf(float f) {
    unsigned u = __float_as_uint(f);
    u = (u + 0x7FFFu + ((u >> 16) & 1u)) >> 16;   // RTN-even
    return (unsigned short)u;
}
__device__ __forceinline__ float bf2f(unsigned short h) {
    unsigned u = ((unsigned)h) << 16;
    return __builtin_bit_cast(float, u);
}
__device__ __forceinline__ unsigned pk2bf(float a, float b) {
    unsigned ua = __float_as_uint(a) + 0x8000u;
    unsigned ub = __float_as_uint(b) + 0x8000u;
    return __builtin_amdgcn_perm(ub, ua, 0x07060302u);
}
__device__ __forceinline__ float gelu_fast(float x) {
    // x * sigmoid(1.5957691*(x+0.044715x^3)) via exp2: one fused poly fma
    float xx = x * x;
    float t  = x * fmaf(xx, -0.1029437f, -2.3022083f);  // -2*sqrt(2/pi)*log2e*(1+c*xx)
    float e  = __builtin_amdgcn_exp2f(t);
    return x * __builtin_amdgcn_rcpf(1.0f + e);
}
__device__ __forceinline__ void sc_ph(unsigned ph, float& sn, float& cs) {
    __sincosf((float)ph * TWO_PI_OVER_L, &sn, &cs);
}
__device__ __forceinline__ void rot(float& c, float& s, float cd, float sd) {
    float cn = fmaf(c, cd, -s * sd);
    s = fmaf(s, cd, c * sd);
    c = cn;
}

#if defined(__has_builtin)
#if __has_builtin(__builtin_amdgcn_mfma_f32_16x16x16bf16_1k)
#define HAVE_MFMA16_1K 1
#endif
#endif
__device__ __forceinline__ void mfma16(f32x4& acc, bfrag4 a, bfrag4 b) {
#ifdef HAVE_MFMA16_1K
    acc = __builtin_amdgcn_mfma_f32_16x16x16bf16_1k(a, b, acc, 0, 0, 0);
#else
    asm("v_mfma_f32_16x16x16_bf16 %0, %1, %2, %0" : "+v"(acc) : "v"(a), "v"(b));
#endif
}

// dedup (last-write-wins): coeff kk survives only if no later j has same index
__device__ __forceinline__ bool keep_coef(const int* __restrict__ idx, int kk) {
    int v = idx[kk];
    bool keep = true;
    for (int j = kk + 1; j < 16; ++j) keep = keep && (idx[j] != v);
    return keep;
}

// ------------------ kernel 1: T1 = x @ U_fc  (512 blocks) -------------------
// U_fc^T rows via rotation chains: 6 sincos/thread (was 128).
__global__ __launch_bounds__(512, 4) void k_t1(
    const float* __restrict__ x,                 // [8192 tok][2048]
    const float* __restrict__ fcr, const float* __restrict__ fci,
    const int* __restrict__ fidx,  const float* __restrict__ fcs,
    unsigned short* __restrict__ t1)             // [512 g][16 tok][32 r] bf16
{
    __shared__ float red[8 * 512];
    const int tid  = threadIdx.x;
    const int w    = tid >> 6;
    const int lane = tid & 63;
    const int lr   = lane & 15;
    const int hi   = lane >> 4;
    const size_t tok0 = (size_t)blockIdx.x * 16;

    const float sc = fcs[0] * (1.0f / 8388608.0f);
    const int p   = lr & 1;
    const int kk0 = lr >> 1, kk1 = 8 + (lr >> 1);
    unsigned s0, s1; float a0, b0, a1, b1;
    {
        bool k0 = keep_coef(fidx, kk0), k1 = keep_coef(fidx, kk1);
        s0 = (((unsigned)fidx[kk0]) << 12) & LMASK;
        s1 = (((unsigned)fidx[kk1]) << 12) & LMASK;
        a0 = k0 ? fcr[kk0] * sc : 0.f;  b0 = k0 ? fci[kk0] * sc : 0.f;
        a1 = k1 ? fcr[kk1] * sc : 0.f;  b1 = k1 ? fci[kk1] * sc : 0.f;
    }
    // e(theta) = alpha*cos(theta) + beta*sin(theta); theta(k) = 2pi*s*k/2^23
    const float al0 = p ? b0 : a0, be0 = p ? a0 : -b0;
    const float al1 = p ? b1 : a1, be1 = p ? a1 : -b1;
    float c1r0, s1r0, c32r0, s32r0, cse0, sse0;   // step-1, step-32, seed
    float c1r1, s1r1, c32r1, s32r1, cse1, sse1;
    {
        const unsigned kb = (unsigned)(w * 256 + hi * 8);
        float sn, cs_;
        sc_ph(s0, sn, cs_);                    c1r0 = cs_;  s1r0 = sn;
        sc_ph((s0 * 32u) & LMASK, sn, cs_);    c32r0 = cs_; s32r0 = sn;
        sc_ph((s0 * kb) & LMASK, sn, cs_);     cse0 = cs_;  sse0 = sn;
        sc_ph(s1, sn, cs_);                    c1r1 = cs_;  s1r1 = sn;
        sc_ph((s1 * 32u) & LMASK, sn, cs_);    c32r1 = cs_; s32r1 = sn;
        sc_ph((s1 * kb) & LMASK, sn, cs_);     cse1 = cs_;  sse1 = sn;
    }

    f32x4 acc[2];
    { f32x4 z = {0.f,0.f,0.f,0.f}; acc[0] = z; acc[1] = z; }
    #pragma unroll 2
    for (int s = 0; s < 8; ++s) {
        int k = w * 256 + s * 32 + hi * 8;
        const float* xp = x + (tok0 + lr) * 2048 + k;
        float4 v0 = *(const float4*)xp;
        float4 v1 = *(const float4*)(xp + 4);
        uint4 aw = make_uint4(pk2bf(v0.x, v0.y), pk2bf(v0.z, v0.w),
                              pk2bf(v1.x, v1.y), pk2bf(v1.z, v1.w));
        bfrag8 af = __builtin_bit_cast(bfrag8, aw);
        float e0[8], e1[8];
        {
            float c = cse0, s_ = sse0;
            #pragma unroll
            for (int t = 0; t < 8; ++t) {
                e0[t] = fmaf(al0, c, be0 * s_);
                if (t < 7) rot(c, s_, c1r0, s1r0);
            }
            rot(cse0, sse0, c32r0, s32r0);     // advance seed to next s-iter
        }
        {
            float c = cse1, s_ = sse1;
            #pragma unroll
            for (int t = 0; t < 8; ++t) {
                e1[t] = fmaf(al1, c, be1 * s_);
                if (t < 7) rot(c, s_, c1r1, s1r1);
            }
            rot(cse1, sse1, c32r1, s32r1);
        }
        uint4 bw0 = make_uint4(pk2bf(e0[0], e0[1]), pk2bf(e0[2], e0[3]),
                               pk2bf(e0[4], e0[5]), pk2bf(e0[6], e0[7]));
        uint4 bw1 = make_uint4(pk2bf(e1[0], e1[1]), pk2bf(e1[2], e1[3]),
                               pk2bf(e1[4], e1[5]), pk2bf(e1[6], e1[7]));
        bfrag8 bf0 = __builtin_bit_cast(bfrag8, bw0);
        bfrag8 bf1 = __builtin_bit_cast(bfrag8, bw1);
        acc[0] = __builtin_amdgcn_mfma_f32_16x16x32_bf16(af, bf0, acc[0], 0, 0, 0);
        acc[1] = __builtin_amdgcn_mfma_f32_16x16x32_bf16(af, bf1, acc[1], 0, 0, 0);
    }
    #pragma unroll
    for (int nj = 0; nj < 2; ++nj)      // C: row=tok(4hi+r), col=r(nj*16+lr)
        #pragma unroll
        for (int r = 0; r < 4; ++r)
            red[w * 512 + (hi * 4 + r) * 32 + nj * 16 + lr] = acc[nj][r];
    __syncthreads();
    float s = 0.f;
    #pragma unroll
    for (int w2 = 0; w2 < 8; ++w2) s += red[w2 * 512 + tid];
    t1[(size_t)blockIdx.x * 512 + tid] = f2bf(s);
}

// -------- kernel 2: middle loop (r11 structure verbatim; slim gelu) ---------
__global__ __launch_bounds__(512, 4) void k_mid(
    const unsigned short* __restrict__ t1,       // [512 g][512]
    const int* __restrict__ fidx,
    const int* __restrict__ pidx,
    const float* __restrict__ prr, const float* __restrict__ pri,
    const float* __restrict__ prs,
    const float* __restrict__ fcb,               // [8192]
    unsigned short* __restrict__ t2p)            // [16 fc][512 g][512] bf16
{
    __shared__ __align__(16) unsigned short vfc[512 * 40];   // 40 KB [f_l][40]
    __shared__ __align__(16) unsigned short upr[32 * 520];   // 33.3 KB [r2][520]
    __shared__ float lbias[512];                             // 2 KB
    const int tid  = threadIdx.x;
    const int w    = tid >> 6;
    const int lane = tid & 63;
    const int lr   = lane & 15;
    const int hi   = lane >> 4;
    const int fc   = blockIdx.x;            // f-chunk 0..15 (512 f each)

    // ---- stage V_fc^T rows: thread t -> f_local t (16 sincos) --------------
    {
        int jg = fc * 512 + tid;
        unsigned m = ((unsigned)jg) >> 1;
        int pj = jg & 1;
        unsigned short* row = vfc + tid * 40;
        #pragma unroll
        for (int k = 0; k < 16; ++k) {
            float sn, cs;
            sc_ph(((((unsigned)fidx[k]) & LMASK) * m) & LMASK, sn, cs);
            row[2 * k]     = f2bf(pj ? sn : cs);
            row[2 * k + 1] = f2bf(pj ? cs : -sn);
        }
    }
    // ---- stage U_pr^T rows: thread t -> (k = t>>5, 16 f) (16 sincos) -------
    {
        const float scp = prs[0] * (1.0f / 8388608.0f);
        int k  = tid >> 5;
        int f0 = (tid & 31) * 16;
        bool kp = keep_coef(pidx, k);
        unsigned s = (((unsigned)pidx[k]) << 10) & LMASK;
        float a = kp ? prr[k] * scp : 0.f;
        float b = kp ? pri[k] * scp : 0.f;
        unsigned short* r0 = upr + (2 * k) * 520 + f0;
        unsigned short* r1 = upr + (2 * k + 1) * 520 + f0;
        unsigned fg = (unsigned)(fc * 512 + f0);
        #pragma unroll
        for (int t = 0; t < 16; ++t) {
            float sn, cs;
            sc_ph((s * (fg + t)) & LMASK, sn, cs);
            r0[t] = f2bf(fmaf(a, cs, -b * sn));
            r1[t] = f2bf(fmaf(a, sn, b * cs));
        }
    }
    lbias[tid] = fcb[fc * 512 + tid];
    __syncthreads();

    // ---- per-wave: 2 token-groups, 16 iters x 32 f, no barriers ------------
    const int ga = blockIdx.y * 16 + w * 2, gb = ga + 1;
    const int toff = lr * 32 + hi * 8;
    const bfrag8 tA = *(const bfrag8*)(t1 + (size_t)ga * 512 + toff);
    const bfrag8 tB = *(const bfrag8*)(t1 + (size_t)gb * 512 + toff);
    f32x4 aA0[2], aA1[2], aB0[2], aB1[2];      // [half]
    #pragma unroll
    for (int h = 0; h < 2; ++h) {
        f32x4 z = {0.f,0.f,0.f,0.f};
        aA0[h] = z; aA1[h] = z; aB0[h] = z; aB1[h] = z;
    }

    #pragma unroll 2
    for (int it = 0; it < 16; ++it) {
        const int f0 = it * 32;
        bfrag8 va0 = *(const bfrag8*)(vfc + (f0 + lr) * 40 + hi * 8);
        bfrag8 va1 = *(const bfrag8*)(vfc + (f0 + 16 + lr) * 40 + hi * 8);
        f32x4 cb0 = *(const f32x4*)(lbias + f0 + hi * 4);
        f32x4 cb1 = *(const f32x4*)(lbias + f0 + 16 + hi * 4);
        bfrag4 u00 = *(const bfrag4*)(upr + lr * 520 + f0 + hi * 4);
        bfrag4 u10 = *(const bfrag4*)(upr + (16 + lr) * 520 + f0 + hi * 4);
        bfrag4 u01 = *(const bfrag4*)(upr + lr * 520 + f0 + 16 + hi * 4);
        bfrag4 u11 = *(const bfrag4*)(upr + (16 + lr) * 520 + f0 + 16 + hi * 4);
        // S tiles: 4 independent chains (group x half)
        f32x4 sA0 = __builtin_amdgcn_mfma_f32_16x16x32_bf16(va0, tA, cb0, 0, 0, 0);
        f32x4 sB0 = __builtin_amdgcn_mfma_f32_16x16x32_bf16(va0, tB, cb0, 0, 0, 0);
        f32x4 sA1 = __builtin_amdgcn_mfma_f32_16x16x32_bf16(va1, tA, cb1, 0, 0, 0);
        f32x4 sB1 = __builtin_amdgcn_mfma_f32_16x16x32_bf16(va1, tB, cb1, 0, 0, 0);
        // gelu + pack (C-layout == K=16 B-frag)
        uint2 hA0 = make_uint2(pk2bf(gelu_fast(sA0[0]), gelu_fast(sA0[1])),
                               pk2bf(gelu_fast(sA0[2]), gelu_fast(sA0[3])));
        uint2 hB0 = make_uint2(pk2bf(gelu_fast(sB0[0]), gelu_fast(sB0[1])),
                               pk2bf(gelu_fast(sB0[2]), gelu_fast(sB0[3])));
        uint2 hA1 = make_uint2(pk2bf(gelu_fast(sA1[0]), gelu_fast(sA1[1])),
                               pk2bf(gelu_fast(sA1[2]), gelu_fast(sA1[3])));
        uint2 hB1 = make_uint2(pk2bf(gelu_fast(sB1[0]), gelu_fast(sB1[1])),
                               pk2bf(gelu_fast(sB1[2]), gelu_fast(sB1[3])));
        bfrag4 fA0 = __builtin_bit_cast(bfrag4, hA0);
        bfrag4 fB0 = __builtin_bit_cast(bfrag4, hB0);
        bfrag4 fA1 = __builtin_bit_cast(bfrag4, hA1);
        bfrag4 fB1 = __builtin_bit_cast(bfrag4, hB1);
        // T2 accumulate: 8 MFMA16 into 8 distinct accumulators
        mfma16(aA0[0], u00, fA0);
        mfma16(aA1[0], u10, fA0);
        mfma16(aB0[0], u00, fB0);
        mfma16(aB1[0], u10, fB0);
        mfma16(aA0[1], u01, fA1);
        mfma16(aA1[1], u11, fA1);
        mfma16(aB0[1], u01, fB1);
        mfma16(aB1[1], u11, fB1);
    }
    f32x4 vA0 = aA0[0] + aA0[1], vA1 = aA1[0] + aA1[1];
    f32x4 vB0 = aB0[0] + aB0[1], vB1 = aB1[0] + aB1[1];

    // ---- direct t2p writes (lane holds r2 = 4hi+r [+16], tok = lr) ---------
    {
        unsigned short* oa = t2p + ((size_t)fc * 512 + ga) * 512;
        unsigned short* ob = t2p + ((size_t)fc * 512 + gb) * 512;
        *(uint2*)(oa + lr * 32 + hi * 4)      = make_uint2(pk2bf(vA0[0], vA0[1]), pk2bf(vA0[2], vA0[3]));
        *(uint2*)(oa + lr * 32 + 16 + hi * 4) = make_uint2(pk2bf(vA1[0], vA1[1]), pk2bf(vA1[2], vA1[3]));
        *(uint2*)(ob + lr * 32 + hi * 4)      = make_uint2(pk2bf(vB0[0], vB0[1]), pk2bf(vB0[2], vB0[3]));
        *(uint2*)(ob + lr * 32 + 16 + hi * 4) = make_uint2(pk2bf(vB1[0], vB1[1]), pk2bf(vB1[2], vB1[3]));
    }
}

// ------ kernel 3: out = (sum_fc T2p) @ V_pr^T + b2  (rotation chains) -------
__global__ __launch_bounds__(512, 4) void k_out(
    const unsigned short* __restrict__ t2p,      // [16][512 g][512] bf16
    const int* __restrict__ pidx,
    const float* __restrict__ prb,               // [2048]
    float* __restrict__ out)                     // [8192 tok][2048]
{
    __shared__ unsigned short lT[512];
    const int tid  = threadIdx.x;
    const int w    = tid >> 6;
    const int lane = tid & 63;
    const int lr   = lane & 15;
    const int hi   = lane >> 4;
    const int g    = blockIdx.x;
    const size_t tok0 = (size_t)g * 16;

    {
        float s = 0.f;
        #pragma unroll
        for (int c = 0; c < 16; ++c)
            s += bf2f(t2p[((size_t)c * 512 + g) * 512 + tid]);
        lT[tid] = f2bf(s);
    }
    // rotators: 4 coeffs (hi selects group); seed at nj=0 (m0), step = 8 units
    const int pd = lr & 1;
    float rc0, rs0, rc1, rs1, rc2, rs2, rc3, rs3;
    float dc0, ds0, dc1, ds1, dc2, ds2, dc3, ds3;
    {
        unsigned m0 = (unsigned)(w * 128 + (lr >> 1));
        float sn, cs_;
        unsigned k0 = ((unsigned)pidx[hi * 4 + 0]) & LMASK;
        unsigned k1 = ((unsigned)pidx[hi * 4 + 1]) & LMASK;
        unsigned k2 = ((unsigned)pidx[hi * 4 + 2]) & LMASK;
        unsigned k3 = ((unsigned)pidx[hi * 4 + 3]) & LMASK;
        sc_ph((k0 * m0) & LMASK, sn, cs_); rc0 = cs_; rs0 = sn;
        sc_ph((k0 * 8u) & LMASK, sn, cs_); dc0 = cs_; ds0 = sn;
        sc_ph((k1 * m0) & LMASK, sn, cs_); rc1 = cs_; rs1 = sn;
        sc_ph((k1 * 8u) & LMASK, sn, cs_); dc1 = cs_; ds1 = sn;
        sc_ph((k2 * m0) & LMASK, sn, cs_); rc2 = cs_; rs2 = sn;
        sc_ph((k2 * 8u) & LMASK, sn, cs_); dc2 = cs_; ds2 = sn;
        sc_ph((k3 * m0) & LMASK, sn, cs_); rc3 = cs_; rs3 = sn;
        sc_ph((k3 * 8u) & LMASK, sn, cs_); dc3 = cs_; ds3 = sn;
    }
    __syncthreads();
    const bfrag8 t2a = *(const bfrag8*)(lT + lr * 32 + hi * 8);
    #pragma unroll 4
    for (int nj = 0; nj < 16; ++nj) {
        int d = w * 256 + nj * 16 + lr;
        // v[2c] = pd ? sin : cos ; v[2c+1] = pd ? cos : -sin
        float v0 = pd ? rs0 : rc0, v1 = pd ? rc0 : -rs0;
        float v2 = pd ? rs1 : rc1, v3 = pd ? rc1 : -rs1;
        float v4 = pd ? rs2 : rc2, v5 = pd ? rc2 : -rs2;
        float v6 = pd ? rs3 : rc3, v7 = pd ? rc3 : -rs3;
        uint4 pw = make_uint4(pk2bf(v0, v1), pk2bf(v2, v3),
                              pk2bf(v4, v5), pk2bf(v6, v7));
        bfrag8 vp = __builtin_bit_cast(bfrag8, pw);
        float bn = prb[d];
        f32x4 c4 = {bn, bn, bn, bn};
        f32x4 o = __builtin_amdgcn_mfma_f32_16x16x32_bf16(t2a, vp, c4, 0, 0, 0);
        #pragma unroll
        for (int r = 0; r < 4; ++r)
            out[(tok0 + hi * 4 + r) * 2048 + d] = o[r];
        rot(rc0, rs0, dc0, ds0);
        rot(rc1, rs1, dc1, ds1);
        rot(rc2, rs2, dc2, ds2);
        rot(rc3, rs3, dc3, ds3);
    }
}

// ---------------------------------------------------------------------------
extern "C" void kernel_launch(void* const* d_in, const int* in_sizes, int n_in,
                              void* d_out, int out_size, void* d_ws, size_t ws_size,
                              hipStream_t stream) {
    (void)in_sizes; (void)n_in; (void)out_size; (void)ws_size;
    const float* x   = (const float*)d_in[0];
    const float* fcr = (const float*)d_in[1];
    const float* fci = (const float*)d_in[2];
    const float* fcs = (const float*)d_in[3];
    const float* prr = (const float*)d_in[4];
    const float* pri = (const float*)d_in[5];
    const float* prs = (const float*)d_in[6];
    const float* fcb = (const float*)d_in[7];
    const float* prb = (const float*)d_in[8];
    const int* fidx  = (const int*)d_in[9];
    const int* pidx  = (const int*)d_in[10];
    float* out = (float*)d_out;
    char* ws = (char*)d_ws;

    size_t off = 0;
    auto take = [&](size_t bytes) { size_t p = off; off = (off + bytes + 255) & ~(size_t)255; return p; };
    unsigned short* t1  = (unsigned short*)(ws + take((size_t)8192 * 32 * 2));       // T1 [8192][32] bf16
    unsigned short* t2p = (unsigned short*)(ws + take((size_t)16 * 8192 * 32 * 2));  // T2 partials bf16

    k_t1 <<<dim3(512),    512, 0, stream>>>(x, fcr, fci, fidx, fcs, t1);
    k_mid<<<dim3(16, 32), 512, 0, stream>>>(t1, fidx, pidx, prr, pri, prs, fcb, t2p);
    k_out<<<dim3(512),    512, 0, stream>>>(t2p, pidx, prb, out);
}